// Round 7
// baseline (458.454 us; speedup 1.0000x reference)
//
#include <hip/hip_runtime.h>
#include <hip/hip_bf16.h>

typedef __attribute__((ext_vector_type(4))) float f32x4;
typedef __attribute__((ext_vector_type(8))) short s16x8;
typedef __attribute__((ext_vector_type(4))) short s16x4;
typedef __attribute__((ext_vector_type(4))) unsigned uintx4;

#define LQS 520   // row stride (shorts) = 1040 B (16B-aligned)

// ONE 66.5 KB buffer, lifetime-folded:
//   phase 1: cols [0,256) = x (bf16)
//   phase 2: cols [0,256)=Q, [256,512)=K  (wave-private 32-col slabs per head)
//   phase 3: la (attn out) overlays own Q slab, cols [0,256)
//   phase 4: fout (proj out, bf16) cols [256,512)
#define SMEM_BYTES (64 * LQS * 2)   // 66560 -> 2 blocks/CU

__device__ __forceinline__ unsigned cvt2bf(float a, float b) {
    unsigned r;
    asm("v_cvt_pk_bf16_f32 %0, %1, %2" : "=v"(r) : "v"(a), "v"(b));
    return r;
}

// K0: weights fp32 -> bf16
__global__ void wcvt_kernel(const float* __restrict__ qw, const float* __restrict__ pw,
                            short* __restrict__ wqkv, short* __restrict__ wproj) {
    int idx = blockIdx.x * blockDim.x + threadIdx.x;
    int stride = gridDim.x * blockDim.x;
    for (int i = idx; i < 65536; i += stride) {
        const float* src = (i < 49152) ? (qw + i * 4) : (pw + (i - 49152) * 4);
        unsigned* dst = (unsigned*)((i < 49152) ? (wqkv + i * 4) : (wproj + (i - 49152) * 4));
        const f32x4 v = *(const f32x4*)src;
        uint2 o = { cvt2bf(v.x, v.y), cvt2bf(v.z, v.w) };
        *(uint2*)dst = o;
    }
}

// K1: bias+mask table, log2 domain. bm[cls][head][i][j], cls=(wy==7)*2+(wx==7)
__global__ void bmgen_kernel(const float* __restrict__ rpb, float* __restrict__ bm) {
    int idx = blockIdx.x * blockDim.x + threadIdx.x;
    if (idx >= 131072) return;
    int j = idx & 63;
    int i = (idx >> 6) & 63;
    int h = (idx >> 12) & 7;
    int c = idx >> 15;
    int cy = c >> 1, cx = c & 1;
    float v;
    if (j >= 49) {
        v = -1e9f;
    } else {
        int ic = i > 48 ? 48 : i;
        int yi = ic / 7, xi = ic % 7;
        int yj = j / 7, xj = j % 7;
        float bias = rpb[((yi - yj + 6) * 13 + (xi - xj + 6)) * 8 + h];
        int ri = (cy ? (yi < 4 ? 1 : 2) : 0) * 3 + (cx ? (xi < 4 ? 1 : 2) : 0);
        int rj = (cy ? (yj < 4 ? 1 : 2) : 0) * 3 + (cx ? (xj < 4 ? 1 : 2) : 0);
        float mask = (ri != rj) ? -100.0f : 0.0f;
        v = (bias + mask) * 1.4426950408889634f;
    }
    bm[idx] = v;
}

__global__ __launch_bounds__(512, 4)
void swin_kernel(const float* __restrict__ x,
                 const float* __restrict__ qkv_bias,
                 const float* __restrict__ proj_bias,
                 const short* __restrict__ wqkv,
                 const short* __restrict__ wproj,
                 const float* __restrict__ bm,
                 float* __restrict__ out) {
    __shared__ __align__(16) short lqk[64 * LQS];

    const int tid  = threadIdx.x;
    const int h    = tid >> 6;        // wave id == head
    const int lane = tid & 63;
    const int il   = lane & 15;
    const int gl   = lane >> 4;

    const int b   = blockIdx.x >> 6;
    const int wid = blockIdx.x & 63;
    const int wy  = wid >> 3, wx = wid & 7;

    // ---------------- stage window x (bf16, cols 0..255) ----------------
    for (int i = tid; i < 4096; i += 512) {  // 64 rows x 64 float4 chunks
        int t = i >> 6, c4 = (i & 63) << 2;
        uint2 o;
        if (t < 49) {
            int ty = t / 7, tx = t % 7;
            int R = wy * 7 + ty + 3; if (R >= 56) R -= 56;
            int C = wx * 7 + tx + 3; if (C >= 56) C -= 56;
            const f32x4 v = *(const f32x4*)(x + (((b * 56 + R) * 56 + C) << 8) + c4);
            o.x = cvt2bf(v.x, v.y); o.y = cvt2bf(v.z, v.w);
        } else {
            o.x = 0; o.y = 0;
        }
        *(uint2*)&lqk[t * LQS + c4] = o;
    }
    __syncthreads();   // (1)

    // ---------------- QKV pass 1: V (head h, 32 cols) -> packed regs --------
    unsigned pv[4][2][2];
    {
        f32x4 vacc[4][2];
        #pragma unroll
        for (int mi = 0; mi < 4; mi++)
            #pragma unroll
            for (int md = 0; md < 2; md++) vacc[mi][md] = (f32x4){0.f, 0.f, 0.f, 0.f};
        for (int k0 = 0; k0 < 256; k0 += 32) {
            s16x8 a[4];
            #pragma unroll
            for (int mi = 0; mi < 4; mi++)
                a[mi] = *(const s16x8*)&lqk[(mi * 16 + il) * LQS + k0 + 8 * gl];
            #pragma unroll
            for (int md = 0; md < 2; md++) {
                s16x8 bfr = *(const s16x8*)(wqkv + (512 + 32 * h + 16 * md + il) * 256 + k0 + 8 * gl);
                #pragma unroll
                for (int mi = 0; mi < 4; mi++)
                    vacc[mi][md] = __builtin_amdgcn_mfma_f32_16x16x32_bf16(a[mi], bfr, vacc[mi][md], 0, 0, 0);
            }
        }
        #pragma unroll
        for (int md = 0; md < 2; md++) {
            float bv = qkv_bias[512 + 32 * h + 16 * md + il];
            #pragma unroll
            for (int mi = 0; mi < 4; mi++) {
                pv[mi][md][0] = cvt2bf(vacc[mi][md][0] + bv, vacc[mi][md][1] + bv);
                pv[mi][md][1] = cvt2bf(vacc[mi][md][2] + bv, vacc[mi][md][3] + bv);
            }
        }
    }

    // ---------------- QKV pass 2: Q,K (head h, 2x32 cols) -------------------
    {
        f32x4 acc[4][4];   // ni 0,1 = Q tiles; ni 2,3 = K tiles
        #pragma unroll
        for (int mi = 0; mi < 4; mi++)
            #pragma unroll
            for (int ni = 0; ni < 4; ni++) acc[mi][ni] = (f32x4){0.f, 0.f, 0.f, 0.f};
        for (int k0 = 0; k0 < 256; k0 += 32) {
            s16x8 a[4];
            #pragma unroll
            for (int mi = 0; mi < 4; mi++)
                a[mi] = *(const s16x8*)&lqk[(mi * 16 + il) * LQS + k0 + 8 * gl];
            #pragma unroll
            for (int ni = 0; ni < 4; ni++) {
                int col = (ni < 2) ? (32 * h + 16 * ni) : (256 + 32 * h + 16 * (ni - 2));
                s16x8 bfr = *(const s16x8*)(wqkv + (col + il) * 256 + k0 + 8 * gl);
                #pragma unroll
                for (int mi = 0; mi < 4; mi++)
                    acc[mi][ni] = __builtin_amdgcn_mfma_f32_16x16x32_bf16(a[mi], bfr, acc[mi][ni], 0, 0, 0);
            }
        }
        __syncthreads();   // (2) all x reads done; buffer becomes Q|K
        {
            const float QSCL = 0.17677669529663687f * 1.4426950408889634f;
            #pragma unroll
            for (int t = 0; t < 2; t++) {
                float bq_ = qkv_bias[32 * h + 16 * t + il];
                float bk_ = qkv_bias[256 + 32 * h + 16 * t + il];
                #pragma unroll
                for (int mi = 0; mi < 4; mi++)
                    #pragma unroll
                    for (int r = 0; r < 4; r++) {
                        int row = mi * 16 + gl * 4 + r;
                        unsigned u = cvt2bf((acc[mi][t][r] + bq_) * QSCL, acc[mi][t + 2][r] + bk_);
                        lqk[row * LQS + 32 * h + 16 * t + il] = (short)u;
                        lqk[row * LQS + 256 + 32 * h + 16 * t + il] = (short)(u >> 16);
                    }
            }
        }
    }
    // no barrier: Q|K slab is wave-private

    // ---------------- attention: head h, full rows, 2 key-halves ------------
    const int cls = ((wy == 7) ? 2 : 0) + ((wx == 7) ? 1 : 0);
    const float* bmp = bm + ((cls * 8 + h) * 64) * 64;

    s16x8 bq[4];
    #pragma unroll
    for (int ni = 0; ni < 4; ni++)
        bq[ni] = *(const s16x8*)&lqk[(ni * 16 + il) * LQS + 32 * h + 8 * gl];

    f32x4 o[2][4];
    #pragma unroll
    for (int md = 0; md < 2; md++)
        #pragma unroll
        for (int ni = 0; ni < 4; ni++) o[md][ni] = (f32x4){0.f, 0.f, 0.f, 0.f};
    float l[4] = { 0.f, 0.f, 0.f, 0.f };

    #pragma unroll 1
    for (int half = 0; half < 2; half++) {
        // scores with bias+mask C-init (log2 domain)
        f32x4 s[2][4];
        #pragma unroll
        for (int mi = 0; mi < 2; mi++)
            #pragma unroll
            for (int ni = 0; ni < 4; ni++)
                s[mi][ni] = *(const f32x4*)&bmp[(ni * 16 + il) * 64 + half * 32 + mi * 16 + gl * 4];
        #pragma unroll
        for (int mi = 0; mi < 2; mi++) {
            s16x8 ak = *(const s16x8*)&lqk[(half * 32 + mi * 16 + il) * LQS + 256 + 32 * h + 8 * gl];
            #pragma unroll
            for (int ni = 0; ni < 4; ni++)
                s[mi][ni] = __builtin_amdgcn_mfma_f32_16x16x32_bf16(ak, bq[ni], s[mi][ni], 0, 0, 0);
        }
        // p = 2^s; accumulate row partial sums (cross-lane reduce deferred)
        #pragma unroll
        for (int mi = 0; mi < 2; mi++)
            #pragma unroll
            for (int ni = 0; ni < 4; ni++)
                #pragma unroll
                for (int r = 0; r < 4; r++) {
                    float p = exp2f(s[mi][ni][r]);
                    s[mi][ni][r] = p;
                    l[ni] += p;
                }
        // pack unnormalized P
        unsigned pkd[2][4][2];
        #pragma unroll
        for (int mi = 0; mi < 2; mi++)
            #pragma unroll
            for (int ni = 0; ni < 4; ni++) {
                pkd[mi][ni][0] = cvt2bf(s[mi][ni][0], s[mi][ni][1]);
                pkd[mi][ni][1] = cvt2bf(s[mi][ni][2], s[mi][ni][3]);
            }
        // select this half's pv words (static-indexed; half is runtime)
        unsigned pva[2][2], pvb[2][2];
        #pragma unroll
        for (int md = 0; md < 2; md++)
            #pragma unroll
            for (int q = 0; q < 2; q++) {
                pva[md][q] = half ? pv[2][md][q] : pv[0][md][q];
                pvb[md][q] = half ? pv[3][md][q] : pv[1][md][q];
            }
        // V A-frags via shuffle
        s16x8 av[2];
        #pragma unroll
        for (int md = 0; md < 2; md++) {
            unsigned wd[4];
            #pragma unroll
            for (int q = 0; q < 4; q++) {
                int src = (2 * (gl & 1) + (q >> 1)) * 16 + il;
                unsigned v0 = (unsigned)__shfl((int)pva[md][q & 1], src);
                unsigned v1 = (unsigned)__shfl((int)pvb[md][q & 1], src);
                wd[q] = (gl & 2) ? v1 : v0;
            }
            union { unsigned u[4]; s16x8 v; } cv;
            cv.u[0] = wd[0]; cv.u[1] = wd[1]; cv.u[2] = wd[2]; cv.u[3] = wd[3];
            av[md] = cv.v;
        }
        // P B-frags via shuffle; PV accumulates into o
        #pragma unroll
        for (int ni = 0; ni < 4; ni++) {
            unsigned wd[4];
            #pragma unroll
            for (int q = 0; q < 4; q++) {
                int src = (2 * (gl & 1) + (q >> 1)) * 16 + il;
                unsigned v0 = (unsigned)__shfl((int)pkd[0][ni][q & 1], src);
                unsigned v1 = (unsigned)__shfl((int)pkd[1][ni][q & 1], src);
                wd[q] = (gl & 2) ? v1 : v0;
            }
            union { unsigned u[4]; s16x8 v; } cv;
            cv.u[0] = wd[0]; cv.u[1] = wd[1]; cv.u[2] = wd[2]; cv.u[3] = wd[3];
            #pragma unroll
            for (int md = 0; md < 2; md++)
                o[md][ni] = __builtin_amdgcn_mfma_f32_16x16x32_bf16(av[md], cv.v, o[md][ni], 0, 0, 0);
        }
    }
    // finish row sums, normalize, write la into own Q slab
    #pragma unroll
    for (int ni = 0; ni < 4; ni++) {
        l[ni] += __shfl_xor(l[ni], 16);
        l[ni] += __shfl_xor(l[ni], 32);
        l[ni] = __builtin_amdgcn_rcpf(l[ni]);
    }
    #pragma unroll
    for (int md = 0; md < 2; md++)
        #pragma unroll
        for (int ni = 0; ni < 4; ni++) {
            uint2 pk = { cvt2bf(o[md][ni][0] * l[ni], o[md][ni][1] * l[ni]),
                         cvt2bf(o[md][ni][2] * l[ni], o[md][ni][3] * l[ni]) };
            *(uint2*)&lqk[(ni * 16 + il) * LQS + 32 * h + md * 16 + gl * 4] = pk;
        }
    __syncthreads();   // (3) all la ready

    // ---------------- proj GEMM: wave h -> out cols [32h,32h+32) ------------
    {
        f32x4 acc[4][2];
        #pragma unroll
        for (int mi = 0; mi < 4; mi++)
            #pragma unroll
            for (int ni = 0; ni < 2; ni++) acc[mi][ni] = (f32x4){0.f, 0.f, 0.f, 0.f};
        for (int k0 = 0; k0 < 256; k0 += 32) {
            s16x8 a[4];
            #pragma unroll
            for (int mi = 0; mi < 4; mi++)
                a[mi] = *(const s16x8*)&lqk[(mi * 16 + il) * LQS + k0 + 8 * gl];
            #pragma unroll
            for (int ni = 0; ni < 2; ni++) {
                s16x8 bw = *(const s16x8*)(wproj + (32 * h + 16 * ni + il) * 256 + k0 + 8 * gl);
                #pragma unroll
                for (int mi = 0; mi < 4; mi++)
                    acc[mi][ni] = __builtin_amdgcn_mfma_f32_16x16x32_bf16(a[mi], bw, acc[mi][ni], 0, 0, 0);
            }
        }
        // fout (bf16) -> cols [256,512), K region (dead); disjoint from la reads
        #pragma unroll
        for (int ni = 0; ni < 2; ni++) {
            int oc = 32 * h + 16 * ni + il;
            float pb = proj_bias[oc];
            #pragma unroll
            for (int mi = 0; mi < 4; mi++)
                #pragma unroll
                for (int r = 0; r < 4; r++) {
                    int t = mi * 16 + gl * 4 + r;
                    if (t < 49) {
                        unsigned u = cvt2bf(acc[mi][ni][r] + pb, 0.f);
                        lqk[t * LQS + 256 + oc] = (short)u;
                    }
                }
        }
    }
    __syncthreads();   // (4)

    // ---------------- coalesced store with reverse roll ---------------------
    for (int i = tid; i < 1568; i += 512) {   // 49 rows x 32 chunks of 8 floats
        int t = i >> 5, c8 = (i & 31) << 3;
        uintx4 u = *(const uintx4*)&lqk[t * LQS + 256 + c8];
        f32x4 v0, v1;
        v0.x = __builtin_bit_cast(float, u.x << 16);
        v0.y = __builtin_bit_cast(float, u.x & 0xFFFF0000u);
        v0.z = __builtin_bit_cast(float, u.y << 16);
        v0.w = __builtin_bit_cast(float, u.y & 0xFFFF0000u);
        v1.x = __builtin_bit_cast(float, u.z << 16);
        v1.y = __builtin_bit_cast(float, u.z & 0xFFFF0000u);
        v1.z = __builtin_bit_cast(float, u.w << 16);
        v1.w = __builtin_bit_cast(float, u.w & 0xFFFF0000u);
        int ty = t / 7, tx = t % 7;
        int R = wy * 7 + ty + 3; if (R >= 56) R -= 56;
        int C = wx * 7 + tx + 3; if (C >= 56) C -= 56;
        float* op = out + (((b * 56 + R) * 56 + C) << 8) + c8;
        *(f32x4*)op = v0;
        *(f32x4*)(op + 4) = v1;
    }
}

extern "C" void kernel_launch(void* const* d_in, const int* in_sizes, int n_in,
                              void* d_out, int out_size, void* d_ws, size_t ws_size,
                              hipStream_t stream) {
    const float* x   = (const float*)d_in[0];
    const float* qw  = (const float*)d_in[1];
    const float* qb  = (const float*)d_in[2];
    const float* pw  = (const float*)d_in[3];
    const float* pb  = (const float*)d_in[4];
    const float* rpb = (const float*)d_in[5];

    short* wqkv  = (short*)d_ws;                       // 768*256 bf16
    short* wproj = wqkv + 768 * 256;                   // 256*256 bf16
    float* bmt   = (float*)((char*)d_ws + 524288);     // 4*8*64*64 f32

    wcvt_kernel<<<128, 256, 0, stream>>>(qw, pw, wqkv, wproj);
    bmgen_kernel<<<512, 256, 0, stream>>>(rpb, bmt);
    swin_kernel<<<2048, 512, 0, stream>>>(x, qb, pb, wqkv, wproj, bmt, (float*)d_out);
}